// Round 1
// baseline (1532.069 us; speedup 1.0000x reference)
//
#include <hip/hip_runtime.h>

#define N_NODES 50000
#define N_EDGES 400000
#define FN 16
#define HH 16
#define NG 64
#define NT 2
#define EPS 1e-5f

// ---------------------------------------------------------------------------
// K1: edge-MLP BN statistics for both convs (pre-BN = e @ W1 + b1), plus
// per-node in-degree counts. stats layout: [m0 sum32 | m0 sq32 | m1 sum32 | m1 sq32]
// ---------------------------------------------------------------------------
__global__ __launch_bounds__(256) void k_edge_stats(
    const float* __restrict__ ea, const int* __restrict__ dst,
    const float* __restrict__ W1a, const float* __restrict__ b1a,
    const float* __restrict__ W1b, const float* __restrict__ b1b,
    float* __restrict__ stats, float* __restrict__ deg)
{
    __shared__ float sW[2][256];
    __shared__ float sb[2][32];
    __shared__ float lacc[128];
    const int tid = threadIdx.x;
    if (tid < 256) { sW[0][tid] = W1a[tid]; sW[1][tid] = W1b[tid]; }
    if (tid < 32)  { sb[0][tid] = b1a[tid]; sb[1][tid] = b1b[tid]; }
    if (tid < 128) lacc[tid] = 0.f;
    __syncthreads();

    const int e = blockIdx.x * 256 + tid;
    const bool valid = (e < N_EDGES);
    float ein[8];
    if (valid) {
        const float4 a4 = ((const float4*)ea)[e * 2];
        const float4 b4 = ((const float4*)ea)[e * 2 + 1];
        ein[0]=a4.x; ein[1]=a4.y; ein[2]=a4.z; ein[3]=a4.w;
        ein[4]=b4.x; ein[5]=b4.y; ein[6]=b4.z; ein[7]=b4.w;
        atomicAdd(deg + dst[e], 1.0f);
    } else {
        #pragma unroll
        for (int j = 0; j < 8; ++j) ein[j] = 0.f;
    }
    const int lane = tid & 63;
    #pragma unroll
    for (int m = 0; m < 2; ++m) {
        #pragma unroll
        for (int k = 0; k < 32; ++k) {
            float p = sb[m][k];
            #pragma unroll
            for (int j = 0; j < 8; ++j) p += ein[j] * sW[m][j * 32 + k];
            float s = valid ? p : 0.f;
            float q = s * p;  // p*p if valid else 0
            #pragma unroll
            for (int o = 32; o; o >>= 1) {
                s += __shfl_down(s, o);
                q += __shfl_down(q, o);
            }
            if (lane == 0) {
                atomicAdd(&lacc[m * 64 + k], s);
                atomicAdd(&lacc[m * 64 + 32 + k], q);
            }
        }
    }
    __syncthreads();
    if (tid < 128) atomicAdd(stats + tid, lacc[tid]);
}

// ---------------------------------------------------------------------------
// K2: fused NNConv edge kernel.  Per edge:
//   h1 = relu(BN(e @ W1 + b1))            (32)
//   msg[o] = sum_i x[src][i] * (sum_k h1[k]*W2[k][i*16+o] + b2[i*16+o])
//   atomicAdd into agg[dst]
// W2 (32KB) + b2 + W1 + BN params staged in LDS (uniform broadcast reads).
// ---------------------------------------------------------------------------
#define ACC4(v4, c, B) { msg[B]+=(c)*(v4).x; msg[(B)+1]+=(c)*(v4).y; \
                         msg[(B)+2]+=(c)*(v4).z; msg[(B)+3]+=(c)*(v4).w; }

__global__ __launch_bounds__(256) void k_conv(
    const float* __restrict__ x, const float* __restrict__ ea,
    const int* __restrict__ src, const int* __restrict__ dst,
    const float* __restrict__ W1, const float* __restrict__ b1,
    const float* __restrict__ gam, const float* __restrict__ bet,
    const float* __restrict__ W2, const float* __restrict__ b2,
    const float* __restrict__ stats, float* __restrict__ agg)
{
    __shared__ float sW2[8192];
    __shared__ float sb2[256];
    __shared__ float sW1[256];
    __shared__ float sb1[32], sscale[32], sshift[32];
    const int tid = threadIdx.x;
    #pragma unroll
    for (int i = 0; i < 8; ++i)
        ((float4*)sW2)[tid + 256 * i] = ((const float4*)W2)[tid + 256 * i];
    if (tid < 64) {
        ((float4*)sb2)[tid] = ((const float4*)b2)[tid];
        ((float4*)sW1)[tid] = ((const float4*)W1)[tid];
    }
    if (tid < 32) {
        const float mean = stats[tid] * (1.0f / N_EDGES);
        const float var  = fmaxf(stats[32 + tid] * (1.0f / N_EDGES) - mean * mean, 0.f);
        const float rs   = rsqrtf(var + EPS);
        const float sc   = gam[tid] * rs;
        sscale[tid] = sc;
        sshift[tid] = bet[tid] - mean * sc;
        sb1[tid]    = b1[tid];
    }
    __syncthreads();

    const int e = blockIdx.x * 256 + tid;
    if (e >= N_EDGES) return;

    const float4 a4 = ((const float4*)ea)[e * 2];
    const float4 b4 = ((const float4*)ea)[e * 2 + 1];
    float ein[8] = {a4.x, a4.y, a4.z, a4.w, b4.x, b4.y, b4.z, b4.w};
    const int s = src[e], d = dst[e];

    const float4* xp = (const float4*)(x + (size_t)s * 16);
    const float4 x0 = xp[0], x1 = xp[1], x2 = xp[2], x3 = xp[3];
    const float xs[16] = {x0.x,x0.y,x0.z,x0.w, x1.x,x1.y,x1.z,x1.w,
                          x2.x,x2.y,x2.z,x2.w, x3.x,x3.y,x3.z,x3.w};

    float h1[32];
    #pragma unroll
    for (int k = 0; k < 32; ++k) {
        float p = sb1[k];
        #pragma unroll
        for (int j = 0; j < 8; ++j) p += ein[j] * sW1[j * 32 + k];
        h1[k] = fmaxf(p * sscale[k] + sshift[k], 0.f);
    }

    float msg[16];
    #pragma unroll
    for (int o = 0; o < 16; ++o) msg[o] = 0.f;

    // bias (b2) term
    #pragma unroll
    for (int i = 0; i < 16; ++i) {
        const float xi = xs[i];
        const float4* bp = (const float4*)(sb2 + i * 16);
        const float4 c0 = bp[0], c1 = bp[1], c2 = bp[2], c3 = bp[3];
        ACC4(c0, xi, 0) ACC4(c1, xi, 4) ACC4(c2, xi, 8) ACC4(c3, xi, 12)
    }
    // main W2 term
    #pragma unroll
    for (int k = 0; k < 32; ++k) {
        const float hk = h1[k];
        const float4* wp = (const float4*)(sW2 + k * 256);
        #pragma unroll
        for (int i = 0; i < 16; ++i) {
            const float c = hk * xs[i];
            const float4 w0 = wp[i*4+0], w1 = wp[i*4+1], w2 = wp[i*4+2], w3 = wp[i*4+3];
            ACC4(w0, c, 0) ACC4(w1, c, 4) ACC4(w2, c, 8) ACC4(w3, c, 12)
        }
    }
    float* ap = agg + (size_t)d * 16;
    #pragma unroll
    for (int o = 0; o < 16; ++o) atomicAdd(ap + o, msg[o]);
}

// ---------------------------------------------------------------------------
// K3: node pre-activation: pre = agg/max(deg,1) + x @ root + bias (in-place in
// agg), accumulate node-BN stats.  Optionally count nodes per graph.
// ---------------------------------------------------------------------------
__global__ __launch_bounds__(256) void k_node_pre(
    float* __restrict__ agg, const float* __restrict__ xin,
    const float* __restrict__ root, const float* __restrict__ bias,
    const float* __restrict__ deg, const int* __restrict__ batch,
    float* gcnt, float* __restrict__ bnstats)
{
    __shared__ float sroot[256], sbias[16], lacc[32];
    const int tid = threadIdx.x;
    if (tid < 64) ((float4*)sroot)[tid] = ((const float4*)root)[tid];
    if (tid < 16) sbias[tid] = bias[tid];
    if (tid < 32) lacc[tid] = 0.f;
    __syncthreads();

    const int n = blockIdx.x * 256 + tid;
    const bool valid = (n < N_NODES);
    float pre[16];
    if (valid) {
        if (gcnt) atomicAdd(gcnt + batch[n], 1.0f);
        const float id = 1.0f / fmaxf(deg[n], 1.0f);
        const float4* ap = (const float4*)(agg + (size_t)n * 16);
        const float4* xp = (const float4*)(xin + (size_t)n * 16);
        const float4 a0=ap[0],a1=ap[1],a2=ap[2],a3=ap[3];
        const float4 x0=xp[0],x1=xp[1],x2=xp[2],x3=xp[3];
        const float av[16] = {a0.x,a0.y,a0.z,a0.w, a1.x,a1.y,a1.z,a1.w,
                              a2.x,a2.y,a2.z,a2.w, a3.x,a3.y,a3.z,a3.w};
        const float xn[16] = {x0.x,x0.y,x0.z,x0.w, x1.x,x1.y,x1.z,x1.w,
                              x2.x,x2.y,x2.z,x2.w, x3.x,x3.y,x3.z,x3.w};
        #pragma unroll
        for (int o = 0; o < 16; ++o) pre[o] = sbias[o] + av[o] * id;
        #pragma unroll
        for (int i = 0; i < 16; ++i) {
            const float xi = xn[i];
            #pragma unroll
            for (int o = 0; o < 16; ++o) pre[o] += xi * sroot[i * 16 + o];
        }
        float4* wp4 = (float4*)(agg + (size_t)n * 16);
        wp4[0] = make_float4(pre[0],pre[1],pre[2],pre[3]);
        wp4[1] = make_float4(pre[4],pre[5],pre[6],pre[7]);
        wp4[2] = make_float4(pre[8],pre[9],pre[10],pre[11]);
        wp4[3] = make_float4(pre[12],pre[13],pre[14],pre[15]);
    } else {
        #pragma unroll
        for (int o = 0; o < 16; ++o) pre[o] = 0.f;
    }
    const int lane = tid & 63;
    #pragma unroll
    for (int o = 0; o < 16; ++o) {
        float s = pre[o], q = s * s;
        #pragma unroll
        for (int w = 32; w; w >>= 1) {
            s += __shfl_down(s, w);
            q += __shfl_down(q, w);
        }
        if (lane == 0) { atomicAdd(&lacc[o], s); atomicAdd(&lacc[16 + o], q); }
    }
    __syncthreads();
    if (tid < 32) atomicAdd(bnstats + tid, lacc[tid]);
}

// ---------------------------------------------------------------------------
// K4: apply node BN + ReLU; optionally write h and/or pool into per-graph sums
// ---------------------------------------------------------------------------
__global__ __launch_bounds__(256) void k_node_bn(
    const float* __restrict__ pre, const float* __restrict__ bnstats,
    const float* __restrict__ gam, const float* __restrict__ bet,
    float* hout, const int* __restrict__ batch, float* pool)
{
    __shared__ float sscale[16], sshift[16];
    const int tid = threadIdx.x;
    if (tid < 16) {
        const float mean = bnstats[tid] * (1.0f / N_NODES);
        const float var  = fmaxf(bnstats[16 + tid] * (1.0f / N_NODES) - mean * mean, 0.f);
        const float rs   = rsqrtf(var + EPS);
        const float sc   = gam[tid] * rs;
        sscale[tid] = sc;
        sshift[tid] = bet[tid] - mean * sc;
    }
    __syncthreads();
    const int n = blockIdx.x * 256 + tid;
    if (n >= N_NODES) return;
    const float4* pp = (const float4*)(pre + (size_t)n * 16);
    const float4 p0=pp[0],p1=pp[1],p2=pp[2],p3=pp[3];
    const float pv[16] = {p0.x,p0.y,p0.z,p0.w, p1.x,p1.y,p1.z,p1.w,
                          p2.x,p2.y,p2.z,p2.w, p3.x,p3.y,p3.z,p3.w};
    float h[16];
    #pragma unroll
    for (int o = 0; o < 16; ++o) h[o] = fmaxf(pv[o] * sscale[o] + sshift[o], 0.f);
    if (hout) {
        float4* hp = (float4*)(hout + (size_t)n * 16);
        hp[0] = make_float4(h[0],h[1],h[2],h[3]);
        hp[1] = make_float4(h[4],h[5],h[6],h[7]);
        hp[2] = make_float4(h[8],h[9],h[10],h[11]);
        hp[3] = make_float4(h[12],h[13],h[14],h[15]);
    }
    if (pool) {
        float* gp = pool + (size_t)batch[n] * 16;
        #pragma unroll
        for (int o = 0; o < 16; ++o) atomicAdd(gp + o, h[o]);
    }
}

// ---------------------------------------------------------------------------
// K5: head MLP over 64 graphs
// ---------------------------------------------------------------------------
__global__ __launch_bounds__(64) void k_head(
    const float* __restrict__ pool, const float* __restrict__ gcnt,
    const float* __restrict__ fc1W, const float* __restrict__ fc1b,
    const float* __restrict__ fc2W, const float* __restrict__ fc2b,
    float* __restrict__ out)
{
    const int g = threadIdx.x;
    if (g >= NG) return;
    const float inv = 1.0f / fmaxf(gcnt[g], 1.0f);
    float p[16];
    #pragma unroll
    for (int o = 0; o < 16; ++o) p[o] = pool[g * 16 + o] * inv;
    float z[16];
    #pragma unroll
    for (int j = 0; j < 16; ++j) {
        float a = fc1b[j];
        #pragma unroll
        for (int o = 0; o < 16; ++o) a += p[o] * fc1W[o * 16 + j];
        z[j] = fmaxf(a, 0.f);
    }
    #pragma unroll
    for (int t = 0; t < NT; ++t) {
        float a = fc2b[t];
        #pragma unroll
        for (int j = 0; j < 16; ++j) a += z[j] * fc2W[j * 2 + t];
        out[g * 2 + t] = a;
    }
}

// ---------------------------------------------------------------------------
extern "C" void kernel_launch(void* const* d_in, const int* in_sizes, int n_in,
                              void* d_out, int out_size, void* d_ws, size_t ws_size,
                              hipStream_t stream)
{
    const float* x    = (const float*)d_in[0];
    const float* ea   = (const float*)d_in[1];
    const float* e1W1 = (const float*)d_in[2];  const float* e1b1 = (const float*)d_in[3];
    const float* e1g  = (const float*)d_in[4];  const float* e1be = (const float*)d_in[5];
    const float* e1W2 = (const float*)d_in[6];  const float* e1b2 = (const float*)d_in[7];
    const float* c1r  = (const float*)d_in[8];  const float* c1b  = (const float*)d_in[9];
    const float* e2W1 = (const float*)d_in[10]; const float* e2b1 = (const float*)d_in[11];
    const float* e2g  = (const float*)d_in[12]; const float* e2be = (const float*)d_in[13];
    const float* e2W2 = (const float*)d_in[14]; const float* e2b2 = (const float*)d_in[15];
    const float* c2r  = (const float*)d_in[16]; const float* c2b  = (const float*)d_in[17];
    const float* bn1g = (const float*)d_in[18]; const float* bn1b = (const float*)d_in[19];
    const float* bn2g = (const float*)d_in[20]; const float* bn2b = (const float*)d_in[21];
    const float* fc1W = (const float*)d_in[22]; const float* fc1b = (const float*)d_in[23];
    const float* fc2W = (const float*)d_in[24]; const float* fc2b = (const float*)d_in[25];
    const int* eidx   = (const int*)d_in[26];
    const int* batch  = (const int*)d_in[27];
    const int* src = eidx;
    const int* dst = eidx + N_EDGES;

    float* ws      = (float*)d_ws;
    float* estats  = ws;                      // 128
    float* bnstats = ws + 128;                // 64
    float* deg     = ws + 192;                // N
    float* gcnt    = deg + N_NODES;           // 64
    float* pool    = gcnt + NG;               // 1024
    float* agg1    = pool + NG * 16;          // N*16 (becomes pre1 in-place)
    float* agg2    = agg1 + (size_t)N_NODES * 16;  // N*16 (becomes pre2 in-place)
    float* h1n     = agg2 + (size_t)N_NODES * 16;  // N*16

    const size_t zero_bytes =
        (size_t)(192 + N_NODES + NG + NG * 16 + 2 * N_NODES * 16) * sizeof(float);
    hipMemsetAsync(d_ws, 0, zero_bytes, stream);

    const int eb = (N_EDGES + 255) / 256;
    const int nb = (N_NODES + 255) / 256;

    k_edge_stats<<<eb, 256, 0, stream>>>(ea, dst, e1W1, e1b1, e2W1, e2b1, estats, deg);
    k_conv<<<eb, 256, 0, stream>>>(x, ea, src, dst, e1W1, e1b1, e1g, e1be,
                                   e1W2, e1b2, estats, agg1);
    k_node_pre<<<nb, 256, 0, stream>>>(agg1, x, c1r, c1b, deg, batch, gcnt, bnstats);
    k_node_bn<<<nb, 256, 0, stream>>>(agg1, bnstats, bn1g, bn1b, h1n, batch, nullptr);
    k_conv<<<eb, 256, 0, stream>>>(h1n, ea, src, dst, e2W1, e2b1, e2g, e2be,
                                   e2W2, e2b2, estats + 64, agg2);
    k_node_pre<<<nb, 256, 0, stream>>>(agg2, h1n, c2r, c2b, deg, batch, nullptr, bnstats + 32);
    k_node_bn<<<nb, 256, 0, stream>>>(agg2, bnstats + 32, bn2g, bn2b, nullptr, batch, pool);
    k_head<<<1, 64, 0, stream>>>(pool, gcnt, fc1W, fc1b, fc2W, fc2b, (float*)d_out);
}

// Round 2
// 449.188 us; speedup vs baseline: 3.4108x; 3.4108x over previous
//
#include <hip/hip_runtime.h>

#define N_NODES 50000
#define N_EDGES 400000
#define NG 64
#define NT 2
#define EPS 1e-5f
#define NB_N ((N_NODES + 255) / 256)   /* 196 */
#define NB_E ((N_EDGES + 255) / 256)   /* 1563 */

// ---------------------------------------------------------------------------
// K1: edge-MLP BN statistics for both convs (pre-BN = e @ W1 + b1), plus
// per-node in-degree counts (int). stats: [m0 sum32 | m0 sq32 | m1 sum32 | m1 sq32]
// ---------------------------------------------------------------------------
__global__ __launch_bounds__(256) void k_edge_stats(
    const float* __restrict__ ea, const int* __restrict__ dst,
    const float* __restrict__ W1a, const float* __restrict__ b1a,
    const float* __restrict__ W1b, const float* __restrict__ b1b,
    float* __restrict__ stats, int* __restrict__ deg)
{
    __shared__ float sW[2][256];
    __shared__ float sb[2][32];
    __shared__ float lacc[128];
    const int tid = threadIdx.x;
    if (tid < 256) { sW[0][tid] = W1a[tid]; sW[1][tid] = W1b[tid]; }
    if (tid < 32)  { sb[0][tid] = b1a[tid]; sb[1][tid] = b1b[tid]; }
    if (tid < 128) lacc[tid] = 0.f;
    __syncthreads();

    const int e = blockIdx.x * 256 + tid;
    const bool valid = (e < N_EDGES);
    float ein[8];
    if (valid) {
        const float4 a4 = ((const float4*)ea)[e * 2];
        const float4 b4 = ((const float4*)ea)[e * 2 + 1];
        ein[0]=a4.x; ein[1]=a4.y; ein[2]=a4.z; ein[3]=a4.w;
        ein[4]=b4.x; ein[5]=b4.y; ein[6]=b4.z; ein[7]=b4.w;
        atomicAdd(deg + dst[e], 1);
    } else {
        #pragma unroll
        for (int j = 0; j < 8; ++j) ein[j] = 0.f;
    }
    const int lane = tid & 63;
    #pragma unroll
    for (int m = 0; m < 2; ++m) {
        #pragma unroll
        for (int k = 0; k < 32; ++k) {
            float p = sb[m][k];
            #pragma unroll
            for (int j = 0; j < 8; ++j) p += ein[j] * sW[m][j * 32 + k];
            float s = valid ? p : 0.f;
            float q = s * p;
            #pragma unroll
            for (int o = 32; o; o >>= 1) {
                s += __shfl_down(s, o);
                q += __shfl_down(q, o);
            }
            if (lane == 0) {
                atomicAdd(&lacc[m * 64 + k], s);
                atomicAdd(&lacc[m * 64 + 32 + k], q);
            }
        }
    }
    __syncthreads();
    if (tid < 128) atomicAdd(stats + tid, lacc[tid]);
}

// ---------------------------------------------------------------------------
// CSR build: block scan of deg -> offsets; pos[e] = slot of edge e in dst-
// sorted order.
// ---------------------------------------------------------------------------
__global__ __launch_bounds__(256) void k_scan1(
    const int* __restrict__ deg, int* __restrict__ loc, int* __restrict__ bsum)
{
    __shared__ int s[256];
    const int t = threadIdx.x;
    const int n = blockIdx.x * 256 + t;
    const int v = (n < N_NODES) ? deg[n] : 0;
    s[t] = v;
    __syncthreads();
    #pragma unroll
    for (int d = 1; d < 256; d <<= 1) {
        const int a = (t >= d) ? s[t - d] : 0;
        __syncthreads();
        s[t] += a;
        __syncthreads();
    }
    if (n < N_NODES) loc[n] = s[t] - v;
    if (t == 255) bsum[blockIdx.x] = s[t];
}

__global__ __launch_bounds__(256) void k_scan2(int* __restrict__ bsum)
{
    __shared__ int s[256];
    const int t = threadIdx.x;
    const int v = (t < NB_N) ? bsum[t] : 0;
    s[t] = v;
    __syncthreads();
    #pragma unroll
    for (int d = 1; d < 256; d <<= 1) {
        const int a = (t >= d) ? s[t - d] : 0;
        __syncthreads();
        s[t] += a;
        __syncthreads();
    }
    if (t < NB_N) bsum[t] = s[t] - v;
}

__global__ __launch_bounds__(256) void k_scan3(
    const int* __restrict__ loc, const int* __restrict__ bsum,
    int* __restrict__ off, int* __restrict__ cur)
{
    const int n = blockIdx.x * 256 + threadIdx.x;
    if (n < N_NODES) {
        const int o = loc[n] + bsum[n >> 8];
        off[n] = o; cur[n] = o;
        if (n == 0) off[N_NODES] = N_EDGES;
    }
}

__global__ __launch_bounds__(256) void k_pos(
    const int* __restrict__ dst, int* __restrict__ cur, int* __restrict__ pos)
{
    const int e = blockIdx.x * 256 + threadIdx.x;
    if (e < N_EDGES) pos[e] = atomicAdd(cur + dst[e], 1);
}

// graph boundaries via binary search (batch is sorted)
__global__ void k_start(const int* __restrict__ batch, int* __restrict__ start)
{
    const int g = threadIdx.x;
    if (g > NG) return;
    int lo = 0, hi = N_NODES;
    while (lo < hi) { const int mid = (lo + hi) >> 1; if (batch[mid] < g) lo = mid + 1; else hi = mid; }
    start[g] = lo;
}

// ---------------------------------------------------------------------------
// K2: fused NNConv edge kernel; writes msg row to its dst-sorted slot.
// ---------------------------------------------------------------------------
#define ACC4(v4, c, B) { msg[B]+=(c)*(v4).x; msg[(B)+1]+=(c)*(v4).y; \
                         msg[(B)+2]+=(c)*(v4).z; msg[(B)+3]+=(c)*(v4).w; }

__global__ __launch_bounds__(256) void k_conv(
    const float* __restrict__ x, const float* __restrict__ ea,
    const int* __restrict__ src,
    const float* __restrict__ W1, const float* __restrict__ b1,
    const float* __restrict__ gam, const float* __restrict__ bet,
    const float* __restrict__ W2, const float* __restrict__ b2,
    const float* __restrict__ stats, const int* __restrict__ pos,
    float* __restrict__ msgbuf)
{
    __shared__ float sW2[8192];
    __shared__ float sb2[256];
    __shared__ float sW1[256];
    __shared__ float sb1[32], sscale[32], sshift[32];
    const int tid = threadIdx.x;
    #pragma unroll
    for (int i = 0; i < 8; ++i)
        ((float4*)sW2)[tid + 256 * i] = ((const float4*)W2)[tid + 256 * i];
    if (tid < 64) {
        ((float4*)sb2)[tid] = ((const float4*)b2)[tid];
        ((float4*)sW1)[tid] = ((const float4*)W1)[tid];
    }
    if (tid < 32) {
        const float mean = stats[tid] * (1.0f / N_EDGES);
        const float var  = fmaxf(stats[32 + tid] * (1.0f / N_EDGES) - mean * mean, 0.f);
        const float rs   = rsqrtf(var + EPS);
        const float sc   = gam[tid] * rs;
        sscale[tid] = sc;
        sshift[tid] = bet[tid] - mean * sc;
        sb1[tid]    = b1[tid];
    }
    __syncthreads();

    const int e = blockIdx.x * 256 + tid;
    if (e >= N_EDGES) return;

    const int p = pos[e];
    const int s = src[e];
    const float4 a4 = ((const float4*)ea)[e * 2];
    const float4 b4 = ((const float4*)ea)[e * 2 + 1];
    float ein[8] = {a4.x, a4.y, a4.z, a4.w, b4.x, b4.y, b4.z, b4.w};

    const float4* xp = (const float4*)(x + (size_t)s * 16);
    const float4 x0 = xp[0], x1 = xp[1], x2 = xp[2], x3 = xp[3];
    const float xs[16] = {x0.x,x0.y,x0.z,x0.w, x1.x,x1.y,x1.z,x1.w,
                          x2.x,x2.y,x2.z,x2.w, x3.x,x3.y,x3.z,x3.w};

    float h1[32];
    #pragma unroll
    for (int k = 0; k < 32; ++k) {
        float pp = sb1[k];
        #pragma unroll
        for (int j = 0; j < 8; ++j) pp += ein[j] * sW1[j * 32 + k];
        h1[k] = fmaxf(pp * sscale[k] + sshift[k], 0.f);
    }

    float msg[16];
    #pragma unroll
    for (int o = 0; o < 16; ++o) msg[o] = 0.f;

    // bias (b2) term
    #pragma unroll
    for (int i = 0; i < 16; ++i) {
        const float xi = xs[i];
        const float4* bp = (const float4*)(sb2 + i * 16);
        const float4 c0 = bp[0], c1 = bp[1], c2 = bp[2], c3 = bp[3];
        ACC4(c0, xi, 0) ACC4(c1, xi, 4) ACC4(c2, xi, 8) ACC4(c3, xi, 12)
    }
    // main W2 term
    #pragma unroll
    for (int k = 0; k < 32; ++k) {
        const float hk = h1[k];
        const float4* wp = (const float4*)(sW2 + k * 256);
        #pragma unroll
        for (int i = 0; i < 16; ++i) {
            const float c = hk * xs[i];
            const float4 w0 = wp[i*4+0], w1 = wp[i*4+1], w2 = wp[i*4+2], w3 = wp[i*4+3];
            ACC4(w0, c, 0) ACC4(w1, c, 4) ACC4(w2, c, 8) ACC4(w3, c, 12)
        }
    }
    float4* mp = (float4*)(msgbuf + (size_t)p * 16);
    mp[0] = make_float4(msg[0],msg[1],msg[2],msg[3]);
    mp[1] = make_float4(msg[4],msg[5],msg[6],msg[7]);
    mp[2] = make_float4(msg[8],msg[9],msg[10],msg[11]);
    mp[3] = make_float4(msg[12],msg[13],msg[14],msg[15]);
}

// ---------------------------------------------------------------------------
// K3: gather node's msg segment (contiguous), mean, + x @ root + bias;
// write pre-activation; accumulate node-BN stats.
// ---------------------------------------------------------------------------
__global__ __launch_bounds__(256) void k_node_pre(
    const float* __restrict__ msg, const int* __restrict__ off,
    const float* __restrict__ xin, const float* __restrict__ root,
    const float* __restrict__ bias, float* __restrict__ bnstats,
    float* __restrict__ pre_out)
{
    __shared__ float sroot[256], sbias[16], lacc[32];
    const int tid = threadIdx.x;
    if (tid < 64) ((float4*)sroot)[tid] = ((const float4*)root)[tid];
    if (tid < 16) sbias[tid] = bias[tid];
    if (tid < 32) lacc[tid] = 0.f;
    __syncthreads();

    const int n = blockIdx.x * 256 + tid;
    const bool valid = (n < N_NODES);
    float pre[16];
    if (valid) {
        const int o0 = off[n], o1 = off[n + 1];
        float acc[16];
        #pragma unroll
        for (int o = 0; o < 16; ++o) acc[o] = 0.f;
        for (int r = o0; r < o1; ++r) {
            const float4* mp = (const float4*)(msg + (size_t)r * 16);
            const float4 m0 = mp[0], m1 = mp[1], m2 = mp[2], m3 = mp[3];
            acc[0]+=m0.x; acc[1]+=m0.y; acc[2]+=m0.z; acc[3]+=m0.w;
            acc[4]+=m1.x; acc[5]+=m1.y; acc[6]+=m1.z; acc[7]+=m1.w;
            acc[8]+=m2.x; acc[9]+=m2.y; acc[10]+=m2.z; acc[11]+=m2.w;
            acc[12]+=m3.x; acc[13]+=m3.y; acc[14]+=m3.z; acc[15]+=m3.w;
        }
        const float inv = 1.0f / (float)max(o1 - o0, 1);
        const float4* xp = (const float4*)(xin + (size_t)n * 16);
        const float4 x0=xp[0],x1=xp[1],x2=xp[2],x3=xp[3];
        const float xn[16] = {x0.x,x0.y,x0.z,x0.w, x1.x,x1.y,x1.z,x1.w,
                              x2.x,x2.y,x2.z,x2.w, x3.x,x3.y,x3.z,x3.w};
        #pragma unroll
        for (int o = 0; o < 16; ++o) pre[o] = sbias[o] + acc[o] * inv;
        #pragma unroll
        for (int i = 0; i < 16; ++i) {
            const float xi = xn[i];
            #pragma unroll
            for (int o = 0; o < 16; ++o) pre[o] += xi * sroot[i * 16 + o];
        }
        float4* wp4 = (float4*)(pre_out + (size_t)n * 16);
        wp4[0] = make_float4(pre[0],pre[1],pre[2],pre[3]);
        wp4[1] = make_float4(pre[4],pre[5],pre[6],pre[7]);
        wp4[2] = make_float4(pre[8],pre[9],pre[10],pre[11]);
        wp4[3] = make_float4(pre[12],pre[13],pre[14],pre[15]);
    } else {
        #pragma unroll
        for (int o = 0; o < 16; ++o) pre[o] = 0.f;
    }
    const int lane = tid & 63;
    #pragma unroll
    for (int o = 0; o < 16; ++o) {
        float s = pre[o], q = s * s;
        #pragma unroll
        for (int w = 32; w; w >>= 1) {
            s += __shfl_down(s, w);
            q += __shfl_down(q, w);
        }
        if (lane == 0) { atomicAdd(&lacc[o], s); atomicAdd(&lacc[16 + o], q); }
    }
    __syncthreads();
    if (tid < 32) atomicAdd(bnstats + tid, lacc[tid]);
}

// ---------------------------------------------------------------------------
// K4: apply node BN + ReLU
// ---------------------------------------------------------------------------
__global__ __launch_bounds__(256) void k_node_bn(
    const float* __restrict__ pre, const float* __restrict__ bnstats,
    const float* __restrict__ gam, const float* __restrict__ bet,
    float* __restrict__ hout)
{
    __shared__ float sscale[16], sshift[16];
    const int tid = threadIdx.x;
    if (tid < 16) {
        const float mean = bnstats[tid] * (1.0f / N_NODES);
        const float var  = fmaxf(bnstats[16 + tid] * (1.0f / N_NODES) - mean * mean, 0.f);
        const float rs   = rsqrtf(var + EPS);
        const float sc   = gam[tid] * rs;
        sscale[tid] = sc;
        sshift[tid] = bet[tid] - mean * sc;
    }
    __syncthreads();
    const int n = blockIdx.x * 256 + tid;
    if (n >= N_NODES) return;
    const float4* pp = (const float4*)(pre + (size_t)n * 16);
    const float4 p0=pp[0],p1=pp[1],p2=pp[2],p3=pp[3];
    const float pv[16] = {p0.x,p0.y,p0.z,p0.w, p1.x,p1.y,p1.z,p1.w,
                          p2.x,p2.y,p2.z,p2.w, p3.x,p3.y,p3.z,p3.w};
    float h[16];
    #pragma unroll
    for (int o = 0; o < 16; ++o) h[o] = fmaxf(pv[o] * sscale[o] + sshift[o], 0.f);
    float4* hp = (float4*)(hout + (size_t)n * 16);
    hp[0] = make_float4(h[0],h[1],h[2],h[3]);
    hp[1] = make_float4(h[4],h[5],h[6],h[7]);
    hp[2] = make_float4(h[8],h[9],h[10],h[11]);
    hp[3] = make_float4(h[12],h[13],h[14],h[15]);
}

// ---------------------------------------------------------------------------
// K5: per-graph mean pool (batch sorted -> contiguous node ranges)
// ---------------------------------------------------------------------------
__global__ __launch_bounds__(256) void k_pool(
    const float* __restrict__ h, const int* __restrict__ start,
    float* __restrict__ pool)
{
    __shared__ float lds[16][16];
    const int g = blockIdx.x;
    const int c = threadIdx.x & 15, rg = threadIdx.x >> 4;
    const int s = start[g], e = start[g + 1];
    float acc = 0.f;
    for (int r = s + rg; r < e; r += 16) acc += h[(size_t)r * 16 + c];
    lds[rg][c] = acc;
    __syncthreads();
    if (threadIdx.x < 16) {
        float sum = 0.f;
        #pragma unroll
        for (int i = 0; i < 16; ++i) sum += lds[i][threadIdx.x];
        const float inv = 1.0f / (float)max(e - s, 1);
        pool[g * 16 + threadIdx.x] = sum * inv;
    }
}

// ---------------------------------------------------------------------------
// K6: head MLP over 64 graphs (pool already mean-divided)
// ---------------------------------------------------------------------------
__global__ __launch_bounds__(64) void k_head(
    const float* __restrict__ pool,
    const float* __restrict__ fc1W, const float* __restrict__ fc1b,
    const float* __restrict__ fc2W, const float* __restrict__ fc2b,
    float* __restrict__ out)
{
    const int g = threadIdx.x;
    if (g >= NG) return;
    float p[16];
    #pragma unroll
    for (int o = 0; o < 16; ++o) p[o] = pool[g * 16 + o];
    float z[16];
    #pragma unroll
    for (int j = 0; j < 16; ++j) {
        float a = fc1b[j];
        #pragma unroll
        for (int o = 0; o < 16; ++o) a += p[o] * fc1W[o * 16 + j];
        z[j] = fmaxf(a, 0.f);
    }
    #pragma unroll
    for (int t = 0; t < NT; ++t) {
        float a = fc2b[t];
        #pragma unroll
        for (int j = 0; j < 16; ++j) a += z[j] * fc2W[j * 2 + t];
        out[g * 2 + t] = a;
    }
}

// ---------------------------------------------------------------------------
extern "C" void kernel_launch(void* const* d_in, const int* in_sizes, int n_in,
                              void* d_out, int out_size, void* d_ws, size_t ws_size,
                              hipStream_t stream)
{
    const float* x    = (const float*)d_in[0];
    const float* ea   = (const float*)d_in[1];
    const float* e1W1 = (const float*)d_in[2];  const float* e1b1 = (const float*)d_in[3];
    const float* e1g  = (const float*)d_in[4];  const float* e1be = (const float*)d_in[5];
    const float* e1W2 = (const float*)d_in[6];  const float* e1b2 = (const float*)d_in[7];
    const float* c1r  = (const float*)d_in[8];  const float* c1b  = (const float*)d_in[9];
    const float* e2W1 = (const float*)d_in[10]; const float* e2b1 = (const float*)d_in[11];
    const float* e2g  = (const float*)d_in[12]; const float* e2be = (const float*)d_in[13];
    const float* e2W2 = (const float*)d_in[14]; const float* e2b2 = (const float*)d_in[15];
    const float* c2r  = (const float*)d_in[16]; const float* c2b  = (const float*)d_in[17];
    const float* bn1g = (const float*)d_in[18]; const float* bn1b = (const float*)d_in[19];
    const float* bn2g = (const float*)d_in[20]; const float* bn2b = (const float*)d_in[21];
    const float* fc1W = (const float*)d_in[22]; const float* fc1b = (const float*)d_in[23];
    const float* fc2W = (const float*)d_in[24]; const float* fc2b = (const float*)d_in[25];
    const int* eidx   = (const int*)d_in[26];
    const int* batch  = (const int*)d_in[27];
    const int* src = eidx;
    const int* dst = eidx + N_EDGES;

    float* ws      = (float*)d_ws;
    float* estats  = ws;                      // 128
    float* bnstats = ws + 128;                // 64
    int* deg_i   = (int*)(ws + 192);          // N (zeroed)
    int* off_i   = deg_i + N_NODES;           // N+1
    int* cur_i   = off_i + N_NODES + 1;       // N
    int* loc_i   = cur_i + N_NODES;           // N
    int* bsum_i  = loc_i + N_NODES;           // 256
    int* start_i = bsum_i + 256;              // NG+1
    int* pos_i   = start_i + NG + 1;          // E
    size_t base = 192 + (size_t)N_NODES * 4 + 1 + 256 + NG + 1 + N_EDGES;
    base = (base + 3) & ~(size_t)3;           // 16B alignment for float4
    float* msg  = ws + base;                  // E*16
    float* pre1 = msg + (size_t)N_EDGES * 16; // N*16 (reused for pre2)
    float* h1n  = pre1 + (size_t)N_NODES * 16;// N*16
    float* pool = h1n + (size_t)N_NODES * 16; // NG*16
    float* h2   = msg;                        // reuse msg region for h2

    hipMemsetAsync(d_ws, 0, (size_t)(192 + N_NODES) * sizeof(float), stream);

    k_edge_stats<<<NB_E, 256, 0, stream>>>(ea, dst, e1W1, e1b1, e2W1, e2b1, estats, deg_i);
    k_scan1<<<NB_N, 256, 0, stream>>>(deg_i, loc_i, bsum_i);
    k_scan2<<<1, 256, 0, stream>>>(bsum_i);
    k_scan3<<<NB_N, 256, 0, stream>>>(loc_i, bsum_i, off_i, cur_i);
    k_pos<<<NB_E, 256, 0, stream>>>(dst, cur_i, pos_i);
    k_start<<<1, 128, 0, stream>>>(batch, start_i);

    k_conv<<<NB_E, 256, 0, stream>>>(x, ea, src, e1W1, e1b1, e1g, e1be,
                                     e1W2, e1b2, estats, pos_i, msg);
    k_node_pre<<<NB_N, 256, 0, stream>>>(msg, off_i, x, c1r, c1b, bnstats, pre1);
    k_node_bn<<<NB_N, 256, 0, stream>>>(pre1, bnstats, bn1g, bn1b, h1n);

    k_conv<<<NB_E, 256, 0, stream>>>(h1n, ea, src, e2W1, e2b1, e2g, e2be,
                                     e2W2, e2b2, estats + 64, pos_i, msg);
    k_node_pre<<<NB_N, 256, 0, stream>>>(msg, off_i, h1n, c2r, c2b, bnstats + 32, pre1);
    k_node_bn<<<NB_N, 256, 0, stream>>>(pre1, bnstats + 32, bn2g, bn2b, h2);

    k_pool<<<NG, 256, 0, stream>>>(h2, start_i, pool);
    k_head<<<1, 64, 0, stream>>>(pool, fc1W, fc1b, fc2W, fc2b, (float*)d_out);
}